// Round 1
// baseline (3431.524 us; speedup 1.0000x reference)
//
#include <hip/hip_runtime.h>
#include <math.h>

#define NN 100000
#define EE 3200000
#define FIN 602
#define HID 256
#define CC 47
#define KSTEPS 10

// ---------------------------------------------------------------- utilities
static __device__ __forceinline__ float wave_sum(float v){
  #pragma unroll
  for (int off = 32; off; off >>= 1) v += __shfl_xor(v, off);
  return v;
}
static __device__ __forceinline__ float wave_max(float v){
  #pragma unroll
  for (int off = 32; off; off >>= 1) v = fmaxf(v, __shfl_xor(v, off));
  return v;
}

// ---------------------------------------------------------------- degree / CSR
__global__ __launch_bounds__(256) void k_count(const int* __restrict__ row, int* __restrict__ cnt){
  int e = blockIdx.x * 256 + threadIdx.x;
  if (e < EE) atomicAdd(&cnt[row[e]], 1);
}

__global__ __launch_bounds__(256) void k_deg(const int* __restrict__ cnt, float* __restrict__ degf){
  int i = blockIdx.x * 256 + threadIdx.x;
  if (i < NN) degf[i] = (float)(cnt[i] + 1);
}

// block of 256 threads scans a 1024-element chunk (exclusive within block)
__global__ __launch_bounds__(256) void k_scanA(const int* __restrict__ cnt, int* __restrict__ rowoff,
                                               int* __restrict__ bsum){
  __shared__ int s[256];
  int t = threadIdx.x, b = blockIdx.x;
  int base = b * 1024 + t * 4;
  int a[4];
  #pragma unroll
  for (int j = 0; j < 4; ++j){ int idx = base + j; a[j] = (idx < NN) ? cnt[idx] : 0; }
  int tsum = a[0] + a[1] + a[2] + a[3];
  s[t] = tsum; __syncthreads();
  for (int off = 1; off < 256; off <<= 1){
    int v = (t >= off) ? s[t - off] : 0;
    __syncthreads();
    s[t] += v;
    __syncthreads();
  }
  int run = s[t] - tsum;               // exclusive prefix for this thread
  #pragma unroll
  for (int j = 0; j < 4; ++j){ int idx = base + j; if (idx <= NN) rowoff[idx] = run; run += a[j]; }
  if (t == 0) bsum[b] = s[255];
}

__global__ __launch_bounds__(256) void k_scanB(const int* __restrict__ bsum, int* __restrict__ boff, int nb){
  __shared__ int s[256];
  int t = threadIdx.x;
  int v = (t < nb) ? bsum[t] : 0;
  s[t] = v; __syncthreads();
  for (int off = 1; off < 256; off <<= 1){
    int u = (t >= off) ? s[t - off] : 0;
    __syncthreads();
    s[t] += u;
    __syncthreads();
  }
  if (t < nb) boff[t] = s[t] - v;      // exclusive block offsets
}

__global__ __launch_bounds__(256) void k_scanC(int* __restrict__ rowoff, int* __restrict__ cursor,
                                               const int* __restrict__ boff){
  int i = blockIdx.x * 256 + threadIdx.x;
  if (i <= NN){
    int v = rowoff[i] + boff[i >> 10];
    rowoff[i] = v;
    if (i < NN) cursor[i] = v;
  }
}

__global__ __launch_bounds__(256) void k_scatter(const int* __restrict__ row, const int* __restrict__ col,
                                                 int* __restrict__ cursor, int* __restrict__ csr_col){
  int e = blockIdx.x * 256 + threadIdx.x;
  if (e < EE){
    int pos = atomicAdd(&cursor[row[e]], 1);
    csr_col[pos] = col[e];
  }
}

// ---------------------------------------------------------------- fused MLP
// h0 = relu(x@W1 + b1)@W2 + b2 ; writes hh = h0 and u0 = dinv * h0
__global__ __launch_bounds__(256) void k_mlp(const float* __restrict__ x, const float* __restrict__ W1,
    const float* __restrict__ b1, const float* __restrict__ W2, const float* __restrict__ b2,
    const float* __restrict__ degf, float* __restrict__ hh, float* __restrict__ u0){
  __shared__ float xs[32][36];     // [kk][r], transposed x tile, padded stride
  __shared__ float ws[32][256];    // W1 chunk [kk][c]
  __shared__ float mid[32][256];   // relu(x@W1+b1) tile
  int t = threadIdx.x;
  int i0 = blockIdx.x * 32;
  int tc = t & 31, tr = t >> 5;    // thread computes rows tr*4..+3, cols tc*8..+7

  float acc[4][8];
  #pragma unroll
  for (int i = 0; i < 4; ++i)
    #pragma unroll
    for (int j = 0; j < 8; ++j) acc[i][j] = 0.0f;

  const int NKC = (FIN + 31) / 32;   // 19 chunks
  for (int kc = 0; kc < NKC; ++kc){
    int k0 = kc * 32;
    int kmax = min(32, FIN - k0);
    __syncthreads();
    // stage x tile (transposed): thread loads 4 consecutive k of one row
    {
      int r = t >> 3, kkb = (t & 7) * 4;
      const float* xp = x + (size_t)(i0 + r) * FIN + k0 + kkb;
      #pragma unroll
      for (int j = 0; j < 4; ++j){
        int kk = kkb + j;
        xs[kk][r] = (k0 + kk < FIN) ? xp[j] : 0.0f;
      }
    }
    // stage W1 chunk: 32 rows x 256 cols, float4 per thread x 8
    {
      int c4 = (t & 63) * 4, kkb = t >> 6;
      #pragma unroll
      for (int l = 0; l < 8; ++l){
        int kk = kkb + l * 4;
        if (kk < kmax){
          *(float4*)&ws[kk][c4] = *(const float4*)(W1 + (size_t)(k0 + kk) * HID + c4);
        }
      }
    }
    __syncthreads();
    for (int kk = 0; kk < kmax; ++kk){
      float xv[4], wv[8];
      *(float4*)xv       = *(const float4*)&xs[kk][tr * 4];
      *(float4*)wv       = *(const float4*)&ws[kk][tc * 8];
      *(float4*)(wv + 4) = *(const float4*)&ws[kk][tc * 8 + 4];
      #pragma unroll
      for (int i = 0; i < 4; ++i)
        #pragma unroll
        for (int j = 0; j < 8; ++j)
          acc[i][j] = fmaf(xv[i], wv[j], acc[i][j]);
    }
  }
  __syncthreads();
  #pragma unroll
  for (int i = 0; i < 4; ++i)
    #pragma unroll
    for (int j = 0; j < 8; ++j){
      float v = acc[i][j] + b1[tc * 8 + j];
      mid[tr * 4 + i][tc * 8 + j] = fmaxf(v, 0.0f);
    }
  __syncthreads();

  // stage2: wave per output row, lane = class; W2 is 48KB -> L1/L2 resident
  int wv2 = t >> 6, lane = t & 63;
  for (int rr = wv2; rr < 32; rr += 4){
    if (lane < CC){
      float a0 = 0, a1 = 0, a2 = 0, a3 = 0;
      #pragma unroll 4
      for (int k = 0; k < HID; k += 4){
        a0 = fmaf(mid[rr][k],     W2[(size_t)(k)     * CC + lane], a0);
        a1 = fmaf(mid[rr][k + 1], W2[(size_t)(k + 1) * CC + lane], a1);
        a2 = fmaf(mid[rr][k + 2], W2[(size_t)(k + 2) * CC + lane], a2);
        a3 = fmaf(mid[rr][k + 3], W2[(size_t)(k + 3) * CC + lane], a3);
      }
      float o = (a0 + a1) + (a2 + a3) + b2[lane];
      int gi = i0 + rr;
      float dinv = 1.0f / sqrtf(degf[gi]);
      hh[(size_t)gi * CC + lane] = o;
      u0[(size_t)gi * CC + lane] = o * dinv;
    }
  }
}

// ---------------------------------------------------------------- AMP step
// u = dinv*h.  p = dinv*(sum_{e in row} u[col] + u[i]) ; y = h - COEF*(h - p)
// z = y - hh ; score = max(||z||-LAM,0)/||z|| ; h' = hh + score*z ; u' = dinv*h'
__global__ __launch_bounds__(256) void k_prop(const int* __restrict__ rowoff, const int* __restrict__ csr_col,
    const float* __restrict__ degf, const float* __restrict__ hh,
    const float* __restrict__ uin, float* __restrict__ uout){
  int w = (blockIdx.x * 256 + threadIdx.x) >> 6;   // one wave per row
  int lane = threadIdx.x & 63;
  if (w >= NN) return;
  int e0 = rowoff[w], e1 = rowoff[w + 1];
  float deg = degf[w];
  float dinv = 1.0f / sqrtf(deg);
  bool act = lane < CC;
  float S = 0.0f, S2 = 0.0f;
  int e = e0;
  for (; e + 1 < e1; e += 2){
    int c0 = csr_col[e], c1 = csr_col[e + 1];
    if (act){
      S  += uin[(size_t)c0 * CC + lane];
      S2 += uin[(size_t)c1 * CC + lane];
    }
  }
  if (e < e1){ int c0 = csr_col[e]; if (act) S += uin[(size_t)c0 * CC + lane]; }
  S += S2;
  float ui = act ? uin[(size_t)w * CC + lane] : 0.0f;
  float hv = act ? hh[(size_t)w * CC + lane] : 0.0f;
  float p = dinv * (S + ui);
  float hcur = ui * sqrtf(deg);
  const float COEF = 1.0f;   // gamma*2*(1-lambda) with lambda=0.5, gamma=1
  const float LAM  = 0.5f;   // gamma*lambda
  float y = hcur - COEF * (hcur - p);
  float z = y - hv;
  float zz = act ? z * z : 0.0f;
  zz = wave_sum(zz);
  float rn = sqrtf(zz);
  float sc = (rn > 0.0f) ? fmaxf(rn - LAM, 0.0f) / rn : 0.0f;
  float hnew = hv + sc * z;
  if (act) uout[(size_t)w * CC + lane] = hnew * dinv;
}

// ---------------------------------------------------------------- log_softmax
__global__ __launch_bounds__(256) void k_lsm(const float* __restrict__ ufin, const float* __restrict__ degf,
                                             float* __restrict__ out){
  int w = (blockIdx.x * 256 + threadIdx.x) >> 6;
  int lane = threadIdx.x & 63;
  if (w >= NN) return;
  float sq = sqrtf(degf[w]);
  bool act = lane < CC;
  float v = act ? ufin[(size_t)w * CC + lane] * sq : -INFINITY;
  float mx = wave_max(v);
  float ex = act ? expf(v - mx) : 0.0f;
  float se = wave_sum(ex);
  float ls = logf(se);
  if (act) out[(size_t)w * CC + lane] = v - mx - ls;
}

// ---------------------------------------------------------------- launcher
extern "C" void kernel_launch(void* const* d_in, const int* in_sizes, int n_in,
                              void* d_out, int out_size, void* d_ws, size_t ws_size,
                              hipStream_t stream){
  const float* x  = (const float*)d_in[0];
  const int*   row = (const int*)d_in[1];
  const int*   col = (const int*)d_in[2];
  const float* W1 = (const float*)d_in[3];
  const float* b1 = (const float*)d_in[4];
  const float* W2 = (const float*)d_in[5];
  const float* b2 = (const float*)d_in[6];
  float* out = (float*)d_out;

  char* ws = (char*)d_ws;
  size_t off = 0;
  auto alloc = [&](size_t bytes) -> char* {
    char* p = ws + off;
    off = (off + bytes + 255) & ~(size_t)255;
    return p;
  };
  int*   cnt     = (int*)  alloc((size_t)NN * 4);
  float* degf    = (float*)alloc((size_t)NN * 4);
  int*   rowoff  = (int*)  alloc((size_t)(NN + 1) * 4);
  int*   cursor  = (int*)  alloc((size_t)NN * 4);
  int*   bsum    = (int*)  alloc(128 * 4);
  int*   boff    = (int*)  alloc(128 * 4);
  int*   csr_col = (int*)  alloc((size_t)EE * 4);
  float* hh      = (float*)alloc((size_t)NN * CC * 4);
  float* u0      = (float*)alloc((size_t)NN * CC * 4);
  float* u1      = (float*)alloc((size_t)NN * CC * 4);

  hipMemsetAsync(cnt, 0, (size_t)NN * 4, stream);
  k_count  <<<(EE + 255) / 256, 256, 0, stream>>>(row, cnt);
  k_deg    <<<(NN + 255) / 256, 256, 0, stream>>>(cnt, degf);
  int nb = (NN + 1 + 1023) / 1024;   // 98
  k_scanA  <<<nb, 256, 0, stream>>>(cnt, rowoff, bsum);
  k_scanB  <<<1, 256, 0, stream>>>(bsum, boff, nb);
  k_scanC  <<<(NN + 1 + 255) / 256, 256, 0, stream>>>(rowoff, cursor, boff);
  k_scatter<<<(EE + 255) / 256, 256, 0, stream>>>(row, col, cursor, csr_col);

  k_mlp<<<NN / 32, 256, 0, stream>>>(x, W1, b1, W2, b2, degf, hh, u0);

  float* ua = u0; float* ub = u1;
  for (int s = 0; s < KSTEPS; ++s){
    k_prop<<<NN / 4, 256, 0, stream>>>(rowoff, csr_col, degf, hh, ua, ub);
    float* tmp = ua; ua = ub; ub = tmp;
  }
  k_lsm<<<NN / 4, 256, 0, stream>>>(ua, degf, out);
}

// Round 2
// 1846.832 us; speedup vs baseline: 1.8581x; 1.8581x over previous
//
#include <hip/hip_runtime.h>
#include <math.h>

#define NN 100000
#define EE 3200000
#define FIN 602
#define HID 256
#define CC 47
#define KSTEPS 10
#define CP 48        // padded class stride (192B = 3 cache lines)
#define KP 608       // padded FIN for bf16 W1t

typedef __attribute__((ext_vector_type(8))) short s8v;      // 8 bf16 (4 VGPR)
typedef __attribute__((ext_vector_type(4))) float f32x4;
typedef __attribute__((ext_vector_type(4))) unsigned short us4;

static __device__ __forceinline__ unsigned short f2bf(float f){
  unsigned int u = __float_as_uint(f);
  unsigned int r = (u + 0x7fffu + ((u >> 16) & 1u)) >> 16;   // RNE
  return (unsigned short)r;
}

static __device__ __forceinline__ float wave_sum(float v){
  #pragma unroll
  for (int off = 32; off; off >>= 1) v += __shfl_xor(v, off);
  return v;
}
static __device__ __forceinline__ float wave_max(float v){
  #pragma unroll
  for (int off = 32; off; off >>= 1) v = fmaxf(v, __shfl_xor(v, off));
  return v;
}

// ---------------------------------------------------------------- degree / CSR
__global__ __launch_bounds__(256) void k_count(const int* __restrict__ row, int* __restrict__ cnt){
  int e = blockIdx.x * 256 + threadIdx.x;
  if (e < EE) atomicAdd(&cnt[row[e]], 1);
}

__global__ __launch_bounds__(256) void k_deg(const int* __restrict__ cnt, float* __restrict__ degf){
  int i = blockIdx.x * 256 + threadIdx.x;
  if (i < NN) degf[i] = (float)(cnt[i] + 1);
}

__global__ __launch_bounds__(256) void k_scanA(const int* __restrict__ cnt, int* __restrict__ rowoff,
                                               int* __restrict__ bsum){
  __shared__ int s[256];
  int t = threadIdx.x, b = blockIdx.x;
  int base = b * 1024 + t * 4;
  int a[4];
  #pragma unroll
  for (int j = 0; j < 4; ++j){ int idx = base + j; a[j] = (idx < NN) ? cnt[idx] : 0; }
  int tsum = a[0] + a[1] + a[2] + a[3];
  s[t] = tsum; __syncthreads();
  for (int off = 1; off < 256; off <<= 1){
    int v = (t >= off) ? s[t - off] : 0;
    __syncthreads();
    s[t] += v;
    __syncthreads();
  }
  int run = s[t] - tsum;
  #pragma unroll
  for (int j = 0; j < 4; ++j){ int idx = base + j; if (idx <= NN) rowoff[idx] = run; run += a[j]; }
  if (t == 0) bsum[b] = s[255];
}

__global__ __launch_bounds__(256) void k_scanB(const int* __restrict__ bsum, int* __restrict__ boff, int nb){
  __shared__ int s[256];
  int t = threadIdx.x;
  int v = (t < nb) ? bsum[t] : 0;
  s[t] = v; __syncthreads();
  for (int off = 1; off < 256; off <<= 1){
    int u = (t >= off) ? s[t - off] : 0;
    __syncthreads();
    s[t] += u;
    __syncthreads();
  }
  if (t < nb) boff[t] = s[t] - v;
}

__global__ __launch_bounds__(256) void k_scanC(int* __restrict__ rowoff, int* __restrict__ cursor,
                                               const int* __restrict__ boff){
  int i = blockIdx.x * 256 + threadIdx.x;
  if (i <= NN){
    int v = rowoff[i] + boff[i >> 10];
    rowoff[i] = v;
    if (i < NN) cursor[i] = v;
  }
}

__global__ __launch_bounds__(256) void k_scatter(const int* __restrict__ row, const int* __restrict__ col,
                                                 int* __restrict__ cursor, int* __restrict__ csr_col){
  int e = blockIdx.x * 256 + threadIdx.x;
  if (e < EE){
    int pos = atomicAdd(&cursor[row[e]], 1);
    csr_col[pos] = col[e];
  }
}

// ---------------------------------------------------------------- weight converts
// W1t[c][k] = bf16(W1[k][c]), c<256, k<602 (zero pad to 608)
__global__ __launch_bounds__(256) void k_cvtW1(const float* __restrict__ W1, unsigned short* __restrict__ W1t){
  int k = blockIdx.x;                 // 0..607
  int c = threadIdx.x;                // 0..255
  float v = (k < FIN) ? W1[(size_t)k * HID + c] : 0.0f;
  W1t[(size_t)c * KP + k] = f2bf(v);
}
// W2t[c][k] = bf16(W2[k][c]), c<48 (row 47 zero), k<256
__global__ __launch_bounds__(256) void k_cvtW2(const float* __restrict__ W2, unsigned short* __restrict__ W2t){
  int c = blockIdx.x;                 // 0..47
  int k = threadIdx.x;                // 0..255
  float v = (c < CC) ? W2[(size_t)k * CC + c] : 0.0f;
  W2t[(size_t)c * HID + k] = f2bf(v);
}

// ---------------------------------------------------------------- fused MFMA MLP
// computes h0 = relu(x@W1+b1)@W2 + b2 for a 64-row block via transposed-D MFMA:
//   D1 = W1^T_frag x^T_frag (per-wave 64 hid-cols x 64 rows), mid in LDS,
//   D2 = W2^T_frag mid^T_frag. Writes hh (f32, stride CP) and u0 = dinv*h0.
__global__ __launch_bounds__(256) void k_mlp(const float* __restrict__ x, const unsigned short* __restrict__ W1t,
    const float* __restrict__ b1, const unsigned short* __restrict__ W2t, const float* __restrict__ b2,
    const float* __restrict__ degf, float* __restrict__ hh, float* __restrict__ u0){
  __shared__ unsigned short xs[64][40];     // x tile bf16, row stride 80B (16B mult)
  __shared__ unsigned short mid[64][264];   // relu(x@W1+b1) bf16, [row][hid]

  const int t = threadIdx.x;
  const int wv = t >> 6, lane = t & 63;
  const int l15 = lane & 15, l4 = lane >> 4;
  const int i0 = blockIdx.x * 64;

  // ---- stage1: acc1[ni][mj] : ni -> hid col frag, mj -> row frag
  f32x4 acc1[4][4];
  #pragma unroll
  for (int a = 0; a < 4; ++a)
    #pragma unroll
    for (int b = 0; b < 4; ++b) acc1[a][b] = (f32x4)0.0f;

  // x staging assignment: row = t>>2 (0..63), kg = t&3 (8 k each)
  const int srow = t >> 2, skg = t & 3;
  const int grow = i0 + srow;
  const bool rok = grow < NN;
  const float* xrow = x + (size_t)grow * FIN;

  // A-frag (W1t) base pointers: c = wv*64 + ni*16 + l15, k-offset l4*8
  const unsigned short* aptr[4];
  #pragma unroll
  for (int ni = 0; ni < 4; ++ni)
    aptr[ni] = W1t + (size_t)(wv * 64 + ni * 16 + l15) * KP + l4 * 8;

  const int NKC = 19;                 // 608/32
  float2 vx[4];
  // preload x regs for chunk 0
  {
    int gk0 = skg * 8;
    #pragma unroll
    for (int jj = 0; jj < 4; ++jj){
      int k = gk0 + jj * 2;
      vx[jj] = (rok && k < FIN) ? *(const float2*)(xrow + k) : make_float2(0.0f, 0.0f);
    }
  }
  s8v af[4];
  #pragma unroll
  for (int ni = 0; ni < 4; ++ni) af[ni] = *(const s8v*)(aptr[ni]);

  for (int kc = 0; kc < NKC; ++kc){
    __syncthreads();
    // write x tile
    {
      s8v xv;
      #pragma unroll
      for (int jj = 0; jj < 4; ++jj){
        xv[jj * 2]     = (short)f2bf(vx[jj].x);
        xv[jj * 2 + 1] = (short)f2bf(vx[jj].y);
      }
      *(s8v*)&xs[srow][skg * 8] = xv;
    }
    __syncthreads();
    // prefetch next chunk x + A frags
    float2 vn[4]; s8v an[4];
    if (kc + 1 < NKC){
      int gk0 = (kc + 1) * 32 + skg * 8;
      #pragma unroll
      for (int jj = 0; jj < 4; ++jj){
        int k = gk0 + jj * 2;
        vn[jj] = (rok && k < FIN) ? *(const float2*)(xrow + k) : make_float2(0.0f, 0.0f);
      }
      #pragma unroll
      for (int ni = 0; ni < 4; ++ni) an[ni] = *(const s8v*)(aptr[ni] + (kc + 1) * 32);
    }
    // B frags from LDS, MFMA
    s8v bf[4];
    #pragma unroll
    for (int mj = 0; mj < 4; ++mj) bf[mj] = *(const s8v*)&xs[mj * 16 + l15][l4 * 8];
    #pragma unroll
    for (int ni = 0; ni < 4; ++ni)
      #pragma unroll
      for (int mj = 0; mj < 4; ++mj)
        acc1[ni][mj] = __builtin_amdgcn_mfma_f32_16x16x32_bf16(af[ni], bf[mj], acc1[ni][mj], 0, 0, 0);
    if (kc + 1 < NKC){
      #pragma unroll
      for (int jj = 0; jj < 4; ++jj) vx[jj] = vn[jj];
      #pragma unroll
      for (int ni = 0; ni < 4; ++ni) af[ni] = an[ni];
    }
  }

  // ---- epilogue1: mid[row j][hid i] = bf16(relu(acc + b1[i]))
  // D frag: j = l15 (+16*mj), i = 4*l4 + reg (+16*ni + 64*wv)
  __syncthreads();
  #pragma unroll
  for (int ni = 0; ni < 4; ++ni){
    int ib = wv * 64 + ni * 16 + l4 * 4;
    float4 b1v = *(const float4*)(b1 + ib);
    #pragma unroll
    for (int mj = 0; mj < 4; ++mj){
      int j = mj * 16 + l15;
      f32x4 a = acc1[ni][mj];
      us4 pk;
      pk[0] = f2bf(fmaxf(a[0] + b1v.x, 0.0f));
      pk[1] = f2bf(fmaxf(a[1] + b1v.y, 0.0f));
      pk[2] = f2bf(fmaxf(a[2] + b1v.z, 0.0f));
      pk[3] = f2bf(fmaxf(a[3] + b1v.w, 0.0f));
      *(us4*)&mid[j][ib] = pk;
    }
  }
  __syncthreads();

  // ---- stage2: per wave 16 rows x 48 classes; K=256 in 8 chunks
  f32x4 acc2[3];
  #pragma unroll
  for (int a = 0; a < 3; ++a) acc2[a] = (f32x4)0.0f;
  const unsigned short* wptr[3];
  #pragma unroll
  for (int ni = 0; ni < 3; ++ni)
    wptr[ni] = W2t + (size_t)(ni * 16 + l15) * HID + l4 * 8;
  #pragma unroll
  for (int kc = 0; kc < 8; ++kc){
    s8v bfr = *(const s8v*)&mid[wv * 16 + l15][kc * 32 + l4 * 8];
    #pragma unroll
    for (int ni = 0; ni < 3; ++ni){
      s8v afr = *(const s8v*)(wptr[ni] + kc * 32);
      acc2[ni] = __builtin_amdgcn_mfma_f32_16x16x32_bf16(afr, bfr, acc2[ni], 0, 0, 0);
    }
  }
  // epilogue2: class i = ni*16 + 4*l4 + r, row j = l15
  {
    int gr = i0 + wv * 16 + l15;
    if (gr < NN){
      float dinv = rsqrtf(degf[gr]);
      #pragma unroll
      for (int ni = 0; ni < 3; ++ni){
        #pragma unroll
        for (int r = 0; r < 4; ++r){
          int i = ni * 16 + l4 * 4 + r;
          if (i < CC){
            float o = acc2[ni][r] + b2[i];
            hh[(size_t)gr * CP + i] = o;
            u0[(size_t)gr * CP + i] = o * dinv;
          }
        }
      }
    }
  }
}

// ---------------------------------------------------------------- AMP step
// u = dinv*h ; p = Âh = dinv*(sum u[col] + u[i]) ; z = p - hh ;
// score = max(||z||-0.5,0)/||z|| ; h' = hh + score*z ; u' = dinv*h'
__global__ __launch_bounds__(256) void k_prop(const int* __restrict__ rowoff, const int* __restrict__ csr_col,
    const float* __restrict__ degf, const float* __restrict__ hh,
    const float* __restrict__ uin, float* __restrict__ uout){
  int w = (blockIdx.x * 256 + threadIdx.x) >> 6;
  int lane = threadIdx.x & 63;
  if (w >= NN) return;
  int e0 = rowoff[w], e1 = rowoff[w + 1];
  int nE = e1 - e0;
  float deg = degf[w];
  float dinv = rsqrtf(deg);
  bool act = lane < CC;
  // hoist own-row loads
  float ui = act ? uin[(size_t)w * CP + lane] : 0.0f;
  float hv = act ? hh[(size_t)w * CP + lane] : 0.0f;
  // cooperative edge-index preload (covers nE<=64; overflow handled below)
  int mycol = (lane < nE) ? csr_col[e0 + lane] : 0;
  int n1 = nE < 64 ? nE : 64;
  float S0 = 0.0f, S1 = 0.0f, S2 = 0.0f, S3 = 0.0f;
  int j = 0;
  for (; j + 3 < n1; j += 4){
    int c0 = __shfl(mycol, j);
    int c1 = __shfl(mycol, j + 1);
    int c2 = __shfl(mycol, j + 2);
    int c3 = __shfl(mycol, j + 3);
    if (act){
      S0 += uin[(size_t)c0 * CP + lane];
      S1 += uin[(size_t)c1 * CP + lane];
      S2 += uin[(size_t)c2 * CP + lane];
      S3 += uin[(size_t)c3 * CP + lane];
    }
  }
  for (; j < n1; ++j){
    int c0 = __shfl(mycol, j);
    if (act) S0 += uin[(size_t)c0 * CP + lane];
  }
  for (int e = e0 + 64; e < e1; ++e){       // rare overflow (deg > 64)
    int c0 = csr_col[e];
    if (act) S0 += uin[(size_t)c0 * CP + lane];
  }
  float S = (S0 + S1) + (S2 + S3);
  float p = dinv * (S + ui);
  float z = p - hv;
  float zz = act ? z * z : 0.0f;
  zz = wave_sum(zz);
  float rn = sqrtf(zz);
  float sc = (rn > 0.0f) ? fmaxf(rn - 0.5f, 0.0f) / rn : 0.0f;
  float hnew = hv + sc * z;
  if (act) uout[(size_t)w * CP + lane] = hnew * dinv;
}

// ---------------------------------------------------------------- log_softmax
__global__ __launch_bounds__(256) void k_lsm(const float* __restrict__ ufin, const float* __restrict__ degf,
                                             float* __restrict__ out){
  int w = (blockIdx.x * 256 + threadIdx.x) >> 6;
  int lane = threadIdx.x & 63;
  if (w >= NN) return;
  float sq = sqrtf(degf[w]);
  bool act = lane < CC;
  float v = act ? ufin[(size_t)w * CP + lane] * sq : -INFINITY;
  float mx = wave_max(v);
  float ex = act ? expf(v - mx) : 0.0f;
  float se = wave_sum(ex);
  float ls = logf(se);
  if (act) out[(size_t)w * CC + lane] = v - mx - ls;
}

// ---------------------------------------------------------------- launcher
extern "C" void kernel_launch(void* const* d_in, const int* in_sizes, int n_in,
                              void* d_out, int out_size, void* d_ws, size_t ws_size,
                              hipStream_t stream){
  const float* x   = (const float*)d_in[0];
  const int*   row = (const int*)d_in[1];
  const int*   col = (const int*)d_in[2];
  const float* W1  = (const float*)d_in[3];
  const float* b1  = (const float*)d_in[4];
  const float* W2  = (const float*)d_in[5];
  const float* b2  = (const float*)d_in[6];
  float* out = (float*)d_out;

  char* ws = (char*)d_ws;
  size_t off = 0;
  auto alloc = [&](size_t bytes) -> char* {
    char* p = ws + off;
    off = (off + bytes + 255) & ~(size_t)255;
    return p;
  };
  int*   cnt     = (int*)  alloc((size_t)NN * 4);
  float* degf    = (float*)alloc((size_t)NN * 4);
  int*   rowoff  = (int*)  alloc((size_t)(NN + 1) * 4);
  int*   cursor  = (int*)  alloc((size_t)NN * 4);
  int*   bsum    = (int*)  alloc(128 * 4);
  int*   boff    = (int*)  alloc(128 * 4);
  int*   csr_col = (int*)  alloc((size_t)EE * 4);
  unsigned short* W1t = (unsigned short*)alloc((size_t)HID * KP * 2);
  unsigned short* W2t = (unsigned short*)alloc((size_t)CP * HID * 2);
  float* hh      = (float*)alloc((size_t)NN * CP * 4);
  float* u0      = (float*)alloc((size_t)NN * CP * 4);
  float* u1      = (float*)alloc((size_t)NN * CP * 4);

  hipMemsetAsync(cnt, 0, (size_t)NN * 4, stream);
  k_count  <<<(EE + 255) / 256, 256, 0, stream>>>(row, cnt);
  k_deg    <<<(NN + 255) / 256, 256, 0, stream>>>(cnt, degf);
  int nb = (NN + 1 + 1023) / 1024;
  k_scanA  <<<nb, 256, 0, stream>>>(cnt, rowoff, bsum);
  k_scanB  <<<1, 256, 0, stream>>>(bsum, boff, nb);
  k_scanC  <<<(NN + 1 + 255) / 256, 256, 0, stream>>>(rowoff, cursor, boff);
  k_scatter<<<(EE + 255) / 256, 256, 0, stream>>>(row, col, cursor, csr_col);

  k_cvtW1<<<KP, 256, 0, stream>>>(W1, W1t);
  k_cvtW2<<<CP, 256, 0, stream>>>(W2, W2t);

  k_mlp<<<(NN + 63) / 64, 256, 0, stream>>>(x, W1t, b1, W2t, b2, degf, hh, u0);

  float* ua = u0; float* ub = u1;
  for (int s = 0; s < KSTEPS; ++s){
    k_prop<<<(NN * 64) / 256, 256, 0, stream>>>(rowoff, csr_col, degf, hh, ua, ub);
    float* tmp = ua; ua = ub; ub = tmp;
  }
  k_lsm<<<(NN * 64) / 256, 256, 0, stream>>>(ua, degf, out);
}